// Round 1
// 423.512 us; speedup vs baseline: 1.0659x; 1.0659x over previous
//
#include <hip/hip_runtime.h>
#include <hip/hip_bf16.h>

#define BDIM 1024
#define VDIM 6890
#define NJ   24
#define NCOL (VDIM*3)   // 20670
#define KPAD 224        // 207 padded to 7*32
#define NPAD 20736      // 81*256 columns for GEMM guardless loads

// fp32-element offsets into d_out (float*):
#define OUT_VERTS   0
#define OUT_JPOSED  21166080
#define OUT_JREST   21239808
#define OUT_A       21313536
#define OUT_VSHAPED 21706752

// Scratch inside the verts region of d_out (dead before k_lbs writes verts).
// Offsets in fp32 elements; pdt/pf are bf16 arrays living in that space.
#define SCRF_PDT    0          // bf16 NPAD*KPAD = 4,644,864 el -> 2,322,432 f32 slots
#define SCRF_PF     2322432    // bf16 1024*224  =   229,376 el ->   114,688 f32 slots
#define SCRF_JTJS   2437120    // 792 f32

typedef __hip_bfloat16 bf16;
typedef unsigned short ushort_t;
typedef __attribute__((ext_vector_type(8))) short  short8;
typedef __attribute__((ext_vector_type(4))) float  float4v;

__device__ __forceinline__ bf16  tob(float x) { return __float2bfloat16(x); }

// ---------------- Kernel A: JT/JS precompute (batch-independent) ----------------
__global__ __launch_bounds__(256) void k_jtjs(const float* __restrict__ jreg,
        const float* __restrict__ vt, const float* __restrict__ sd,
        float* __restrict__ jtjs) {
    int j = blockIdx.x;
    int tid = threadIdx.x;
    float acc[33];
#pragma unroll
    for (int i = 0; i < 33; i++) acc[i] = 0.f;
    for (int v = tid; v < VDIM; v += 256) {
        float r = jreg[j*VDIM + v];
#pragma unroll
        for (int m = 0; m < 3; m++) {
            acc[m] += r * vt[v*3+m];
#pragma unroll
            for (int l = 0; l < 10; l++)
                acc[3 + m*10 + l] += r * sd[(v*3+m)*10 + l];
        }
    }
    __shared__ float red[4][33];
    int lane = tid & 63, wid = tid >> 6;
#pragma unroll
    for (int i = 0; i < 33; i++) {
        float x = acc[i];
        for (int off = 32; off > 0; off >>= 1) x += __shfl_down(x, off);
        if (lane == 0) red[wid][i] = x;
    }
    __syncthreads();
    if (tid < 33)
        jtjs[j*33 + tid] = red[0][tid] + red[1][tid] + red[2][tid] + red[3][tid];
}

// ---------------- Kernel PT: transpose posedirs f32 (207 x 20670) -> bf16 (NPAD x 224) ----------------
__global__ __launch_bounds__(256) void k_transpose(const float* __restrict__ pd,
        bf16* __restrict__ pdt) {
    __shared__ bf16 tile[32][65];
    int nt = blockIdx.x * 64;
    int kt = blockIdx.y * 32;
    int t = threadIdx.x;
    for (int i = t; i < 32*64; i += 256) {
        int kk = i >> 6, nn = i & 63;
        int k = kt + kk, n = nt + nn;
        float v = 0.f;
        if (k < 207 && n < NCOL) v = pd[k*NCOL + n];
        tile[kk][nn] = tob(v);
    }
    __syncthreads();
    for (int i = t; i < 32*64; i += 256) {
        int kk = i & 31, nn = i >> 5;
        pdt[(nt + nn)*KPAD + kt + kk] = tile[kk][nn];
    }
}

// ---------------- Kernel B: per-batch pose (Rodrigues, chain, A, J_rest, J_posed) ----------------
__global__ __launch_bounds__(64) void k_pose(const float* __restrict__ betas,
        const float* __restrict__ pose, const int* __restrict__ parents,
        const float* __restrict__ jtjs, float* __restrict__ out,
        bf16* __restrict__ wspf) {
    int b = blockIdx.x, t = threadIdx.x;
    __shared__ float R[24][9];
    __shared__ float jrest[24][3];
    __shared__ float rel[24][3];
    __shared__ float ch[24][12];
    __shared__ int par[24];
    if (t < 24) {
        par[t] = parents[t];
        float rx = pose[b*72 + t*3 + 0];
        float ry = pose[b*72 + t*3 + 1];
        float rz = pose[b*72 + t*3 + 2];
        float ax = rx + 1e-8f, ay = ry + 1e-8f, az = rz + 1e-8f;
        float angle = sqrtf(ax*ax + ay*ay + az*az);
        float inv = 1.0f / angle;               // axis = original r / angle (ref semantics)
        float kx = rx*inv, ky = ry*inv, kz = rz*inv;
        float s = sinf(angle), c = cosf(angle);
        float t1 = 1.0f - c;
        float q = kx*kx + ky*ky + kz*kz;        // K^2 = kk^T - (k.k) I
        R[t][0] = 1.f + t1*(kx*kx - q);
        R[t][1] = -s*kz + t1*kx*ky;
        R[t][2] =  s*ky + t1*kx*kz;
        R[t][3] =  s*kz + t1*kx*ky;
        R[t][4] = 1.f + t1*(ky*ky - q);
        R[t][5] = -s*kx + t1*ky*kz;
        R[t][6] = -s*ky + t1*kx*kz;
        R[t][7] =  s*kx + t1*ky*kz;
        R[t][8] = 1.f + t1*(kz*kz - q);
    }
    __syncthreads();
    // pose_feature -> scratch (bf16, zero-padded to KPAD)
    for (int i = t; i < KPAD; i += 64) {
        float pf = 0.f;
        if (i < 207) {
            int j = i/9 + 1, e = i - (j-1)*9;
            pf = R[j][e] - ((e == 0 || e == 4 || e == 8) ? 1.f : 0.f);
        }
        wspf[b*KPAD + i] = tob(pf);
    }
    // J_rest = JT + JS . betas   (64 threads -> strided loop over 72)
    for (int i = t; i < 72; i += 64) {
        int j = i/3, k = i - j*3;
        const float* JJ = &jtjs[j*33];
        float s = JJ[k];
#pragma unroll
        for (int l = 0; l < 10; l++) s += JJ[3 + k*10 + l] * betas[b*10 + l];
        jrest[j][k] = s;
        out[OUT_JREST + b*72 + i] = s;
    }
    __syncthreads();
    for (int i = t; i < 72; i += 64) {
        int j = i/3, k = i - j*3;
        rel[j][k] = jrest[j][k] - (j > 0 ? jrest[par[j]][k] : 0.f);
    }
    __syncthreads();
    if (t < 12) {
        int m = t >> 2, n = t & 3;
        ch[0][t] = (n < 3) ? R[0][m*3+n] : rel[0][m];
    }
    __syncthreads();
    for (int i = 1; i < 24; i++) {
        float val = 0.f;
        if (t < 12) {
            int m = t >> 2, n = t & 3;
            int p = par[i];                      // p < i: no overlap with ch[i] write
            if (n < 3)
                val = ch[p][m*4+0]*R[i][n] + ch[p][m*4+1]*R[i][3+n] + ch[p][m*4+2]*R[i][6+n];
            else
                val = ch[p][m*4+0]*rel[i][0] + ch[p][m*4+1]*rel[i][1]
                    + ch[p][m*4+2]*rel[i][2] + ch[p][m*4+3];
        }
        if (t < 12) ch[i][t] = val;
        __syncthreads();
    }
    for (int i = t; i < 72; i += 64) {
        int j = i/3, k = i - j*3;
        out[OUT_JPOSED + b*72 + i] = ch[j][k*4+3];
    }
    // A = chain with translation t - R*jrest (fp32 output; k_lbs re-reads it)
    for (int i = t; i < 384; i += 64) {
        int j = i >> 4, e = i & 15, m = e >> 2, n = e & 3;
        float v;
        if (m < 3) {
            if (n < 3) v = ch[j][m*4+n];
            else v = ch[j][m*4+3] - (ch[j][m*4+0]*jrest[j][0] + ch[j][m*4+1]*jrest[j][1]
                                   + ch[j][m*4+2]*jrest[j][2]);
        } else v = (n == 3) ? 1.f : 0.f;
        out[OUT_A + b*384 + i] = v;
    }
}

// ---------------- Kernel D: pose GEMM via MFMA: delta = pf (B x 224) @ posedirs (224 x 20670) ----------------
__global__ __launch_bounds__(256) void k_posegemm(const bf16* __restrict__ wspf,
        const bf16* __restrict__ wspdt, float* __restrict__ dout) {
    const ushort_t* pf  = (const ushort_t*)wspf;
    const ushort_t* pdt = (const ushort_t*)wspdt;
    int lane = threadIdx.x & 63;
    int wave = threadIdx.x >> 6;
    int l15 = lane & 15, quad = lane >> 4;
    int m0 = blockIdx.y * 32;
    int n0 = blockIdx.x * 256 + wave * 64;
    float4v acc[2][4] = {};
    for (int c = 0; c < 7; c++) {
        short8 a[2], bb[4];
#pragma unroll
        for (int mf = 0; mf < 2; mf++)
            a[mf] = *reinterpret_cast<const short8*>(pf + (m0 + mf*16 + l15)*KPAD + c*32 + quad*8);
#pragma unroll
        for (int nf = 0; nf < 4; nf++)
            bb[nf] = *reinterpret_cast<const short8*>(pdt + (n0 + nf*16 + l15)*KPAD + c*32 + quad*8);
#pragma unroll
        for (int mf = 0; mf < 2; mf++)
#pragma unroll
            for (int nf = 0; nf < 4; nf++)
                acc[mf][nf] = __builtin_amdgcn_mfma_f32_16x16x32_bf16(a[mf], bb[nf], acc[mf][nf], 0, 0, 0);
    }
#pragma unroll
    for (int mf = 0; mf < 2; mf++)
#pragma unroll
        for (int nf = 0; nf < 4; nf++) {
            int col = n0 + nf*16 + l15;
            if (col < NCOL) {
#pragma unroll
                for (int r = 0; r < 4; r++) {
                    int row = m0 + mf*16 + quad*4 + r;   // C/D: col=lane&15, row=quad*4+reg
                    dout[row*NCOL + col] = acc[mf][nf][r];
                }
            }
        }
}

// ---------------- Kernel E: v_shaped + LBS + verts ----------------
// A is wave-uniform per block (b = blockIdx.y): read it through a separate
// __restrict__ pointer so the backend's no-clobber check passes and the
// loads scalarize to s_load_* (SGPR operands into v_fmac). This removes the
// 72 ds_read_b128/thread LDS broadcast that was the previous bottleneck
// (432 waves/CU x 72 x ~12cy ~= 155 us of LDS-pipe serialization).
__global__ __launch_bounds__(256) void k_lbs(const float* __restrict__ betas,
        const float* __restrict__ sd, const float* __restrict__ vt,
        const float* __restrict__ lbs, const float* __restrict__ Amat,
        float* __restrict__ out) {
    int tid = threadIdx.x;
    int b = blockIdx.y;
    int v = blockIdx.x*256 + tid;
    if (v >= VDIM) return;

    const float* __restrict__ Ab = Amat + (size_t)b*384;   // uniform address

    // 24 LBS weights, vectorized 16B loads (v*96 bytes is 16B-aligned)
    float w[24];
    {
        const float4v* W4 = reinterpret_cast<const float4v*>(lbs + v*24);
#pragma unroll
        for (int q = 0; q < 6; q++) {
            float4v x = W4[q];
#pragma unroll
            for (int e = 0; e < 4; e++) w[q*4+e] = x[e];
        }
    }

    // T = sum_j w_j * A_j  (A_j rows m<3; SGPR source per fmac)
    float T[12];
#pragma unroll
    for (int e = 0; e < 12; e++) T[e] = 0.f;
#pragma unroll
    for (int j = 0; j < 24; j++) {
#pragma unroll
        for (int e = 0; e < 12; e++)
            T[e] = fmaf(w[j], Ab[j*16 + e], T[e]);
    }

    // v_shaped (betas[b*10+l] is uniform -> SGPRs too)
    float vs[3];
#pragma unroll
    for (int m = 0; m < 3; m++) {
        float s = vt[v*3 + m];
#pragma unroll
        for (int l = 0; l < 10; l++) s += betas[b*10 + l] * sd[(v*3+m)*10 + l];
        vs[m] = s;
    }

    float* vsh = out + OUT_VSHAPED;
    int base = b*NCOL + v*3;
    float vp0 = vs[0] + vsh[base + 0];
    float vp1 = vs[1] + vsh[base + 1];
    float vp2 = vs[2] + vsh[base + 2];
#pragma unroll
    for (int m = 0; m < 3; m++) {
        float o = T[m*4+3] + T[m*4]*vp0 + T[m*4+1]*vp1 + T[m*4+2]*vp2;
        out[base + m] = o;             // verts at offset 0
        vsh[base + m] = vs[m];         // overwrite scratch with v_shaped
    }
}

extern "C" void kernel_launch(void* const* d_in, const int* in_sizes, int n_in,
                              void* d_out, int out_size, void* d_ws, size_t ws_size,
                              hipStream_t stream) {
    // Bind inputs BY SIZE (robust to dict-order vs alphabetical flattening;
    // the 165360 pair J_regressor/lbs_weights keeps relative order in both).
    const float *betas = nullptr, *pose = nullptr, *vt = nullptr, *sd = nullptr,
                *pd = nullptr, *jreg = nullptr, *lbs = nullptr;
    const int* parents = nullptr;
    for (int i = 0; i < n_in; i++) {
        switch (in_sizes[i]) {
            case 10240:   betas = (const float*)d_in[i]; break;      // (1024,10)
            case 73728:   pose  = (const float*)d_in[i]; break;      // (1024,72)
            case 20670:   vt    = (const float*)d_in[i]; break;      // (1,6890,3)
            case 206700:  sd    = (const float*)d_in[i]; break;      // (6890,3,10)
            case 4278690: pd    = (const float*)d_in[i]; break;      // (207,20670)
            case 24:      parents = (const int*)d_in[i]; break;      // (24,)
            case 165360:                                             // (24,6890)/(6890,24)
                if (!jreg) jreg = (const float*)d_in[i];
                else       lbs  = (const float*)d_in[i];
                break;
            default: break;
        }
    }
    float* out = (float*)d_out;   // reference output dtype is float32
    (void)d_ws; (void)ws_size;

    // Scratch in the verts region of d_out (dead before k_lbs writes verts):
    bf16*  ws_pdt  = (bf16*)(out + SCRF_PDT);
    bf16*  ws_pf   = (bf16*)(out + SCRF_PF);
    float* ws_jtjs = out + SCRF_JTJS;

    k_jtjs<<<24, 256, 0, stream>>>(jreg, vt, sd, ws_jtjs);
    k_transpose<<<dim3(324, 7), 256, 0, stream>>>(pd, ws_pdt);
    k_pose<<<BDIM, 64, 0, stream>>>(betas, pose, parents, ws_jtjs, out, ws_pf);
    k_posegemm<<<dim3(81, 32), 256, 0, stream>>>(ws_pf, ws_pdt, out + OUT_VSHAPED);
    k_lbs<<<dim3(27, BDIM), 256, 0, stream>>>(betas, sd, vt, lbs, out + OUT_A, out);
}

// Round 2
// 370.770 us; speedup vs baseline: 1.2175x; 1.1422x over previous
//
#include <hip/hip_runtime.h>
#include <hip/hip_bf16.h>

#define BDIM 1024
#define VDIM 6890
#define NJ   24
#define NCOL (VDIM*3)   // 20670
#define KPAD 224        // 207 padded to 7*32
#define NPAD 20736      // 81*256 columns for GEMM guardless loads
#define NB   8          // batches per k_lbs block (batch-tiling)

// fp32-element offsets into d_out (float*):
#define OUT_VERTS   0
#define OUT_JPOSED  21166080
#define OUT_JREST   21239808
#define OUT_A       21313536
#define OUT_VSHAPED 21706752

// Scratch inside the verts region of d_out (dead before k_lbs writes verts).
// Offsets in fp32 elements; pdt/pf are bf16 arrays living in that space.
#define SCRF_PDT    0          // bf16 NPAD*KPAD = 4,644,864 el -> 2,322,432 f32 slots
#define SCRF_PF     2322432    // bf16 1024*224  =   229,376 el ->   114,688 f32 slots
#define SCRF_JTJS   2437120    // 792 f32

typedef __hip_bfloat16 bf16;
typedef unsigned short ushort_t;
typedef __attribute__((ext_vector_type(8))) short  short8;
typedef __attribute__((ext_vector_type(4))) float  float4v;

__device__ __forceinline__ bf16  tob(float x) { return __float2bfloat16(x); }

// ---------------- Kernel A: JT/JS precompute (batch-independent) ----------------
__global__ __launch_bounds__(256) void k_jtjs(const float* __restrict__ jreg,
        const float* __restrict__ vt, const float* __restrict__ sd,
        float* __restrict__ jtjs) {
    int j = blockIdx.x;
    int tid = threadIdx.x;
    float acc[33];
#pragma unroll
    for (int i = 0; i < 33; i++) acc[i] = 0.f;
    for (int v = tid; v < VDIM; v += 256) {
        float r = jreg[j*VDIM + v];
#pragma unroll
        for (int m = 0; m < 3; m++) {
            acc[m] += r * vt[v*3+m];
#pragma unroll
            for (int l = 0; l < 10; l++)
                acc[3 + m*10 + l] += r * sd[(v*3+m)*10 + l];
        }
    }
    __shared__ float red[4][33];
    int lane = tid & 63, wid = tid >> 6;
#pragma unroll
    for (int i = 0; i < 33; i++) {
        float x = acc[i];
        for (int off = 32; off > 0; off >>= 1) x += __shfl_down(x, off);
        if (lane == 0) red[wid][i] = x;
    }
    __syncthreads();
    if (tid < 33)
        jtjs[j*33 + tid] = red[0][tid] + red[1][tid] + red[2][tid] + red[3][tid];
}

// ---------------- Kernel PT: transpose posedirs f32 (207 x 20670) -> bf16 (NPAD x 224) ----------------
__global__ __launch_bounds__(256) void k_transpose(const float* __restrict__ pd,
        bf16* __restrict__ pdt) {
    __shared__ bf16 tile[32][65];
    int nt = blockIdx.x * 64;
    int kt = blockIdx.y * 32;
    int t = threadIdx.x;
    for (int i = t; i < 32*64; i += 256) {
        int kk = i >> 6, nn = i & 63;
        int k = kt + kk, n = nt + nn;
        float v = 0.f;
        if (k < 207 && n < NCOL) v = pd[k*NCOL + n];
        tile[kk][nn] = tob(v);
    }
    __syncthreads();
    for (int i = t; i < 32*64; i += 256) {
        int kk = i & 31, nn = i >> 5;
        pdt[(nt + nn)*KPAD + kt + kk] = tile[kk][nn];
    }
}

// ---------------- Kernel B: per-batch pose (Rodrigues, chain, A, J_rest, J_posed) ----------------
__global__ __launch_bounds__(64) void k_pose(const float* __restrict__ betas,
        const float* __restrict__ pose, const int* __restrict__ parents,
        const float* __restrict__ jtjs, float* __restrict__ out,
        bf16* __restrict__ wspf) {
    int b = blockIdx.x, t = threadIdx.x;
    __shared__ float R[24][9];
    __shared__ float jrest[24][3];
    __shared__ float rel[24][3];
    __shared__ float ch[24][12];
    __shared__ int par[24];
    if (t < 24) {
        par[t] = parents[t];
        float rx = pose[b*72 + t*3 + 0];
        float ry = pose[b*72 + t*3 + 1];
        float rz = pose[b*72 + t*3 + 2];
        float ax = rx + 1e-8f, ay = ry + 1e-8f, az = rz + 1e-8f;
        float angle = sqrtf(ax*ax + ay*ay + az*az);
        float inv = 1.0f / angle;               // axis = original r / angle (ref semantics)
        float kx = rx*inv, ky = ry*inv, kz = rz*inv;
        float s = sinf(angle), c = cosf(angle);
        float t1 = 1.0f - c;
        float q = kx*kx + ky*ky + kz*kz;        // K^2 = kk^T - (k.k) I
        R[t][0] = 1.f + t1*(kx*kx - q);
        R[t][1] = -s*kz + t1*kx*ky;
        R[t][2] =  s*ky + t1*kx*kz;
        R[t][3] =  s*kz + t1*kx*ky;
        R[t][4] = 1.f + t1*(ky*ky - q);
        R[t][5] = -s*kx + t1*ky*kz;
        R[t][6] = -s*ky + t1*kx*kz;
        R[t][7] =  s*kx + t1*ky*kz;
        R[t][8] = 1.f + t1*(kz*kz - q);
    }
    __syncthreads();
    // pose_feature -> scratch (bf16, zero-padded to KPAD)
    for (int i = t; i < KPAD; i += 64) {
        float pf = 0.f;
        if (i < 207) {
            int j = i/9 + 1, e = i - (j-1)*9;
            pf = R[j][e] - ((e == 0 || e == 4 || e == 8) ? 1.f : 0.f);
        }
        wspf[b*KPAD + i] = tob(pf);
    }
    // J_rest = JT + JS . betas   (64 threads -> strided loop over 72)
    for (int i = t; i < 72; i += 64) {
        int j = i/3, k = i - j*3;
        const float* JJ = &jtjs[j*33];
        float s = JJ[k];
#pragma unroll
        for (int l = 0; l < 10; l++) s += JJ[3 + k*10 + l] * betas[b*10 + l];
        jrest[j][k] = s;
        out[OUT_JREST + b*72 + i] = s;
    }
    __syncthreads();
    for (int i = t; i < 72; i += 64) {
        int j = i/3, k = i - j*3;
        rel[j][k] = jrest[j][k] - (j > 0 ? jrest[par[j]][k] : 0.f);
    }
    __syncthreads();
    if (t < 12) {
        int m = t >> 2, n = t & 3;
        ch[0][t] = (n < 3) ? R[0][m*3+n] : rel[0][m];
    }
    __syncthreads();
    for (int i = 1; i < 24; i++) {
        float val = 0.f;
        if (t < 12) {
            int m = t >> 2, n = t & 3;
            int p = par[i];                      // p < i: no overlap with ch[i] write
            if (n < 3)
                val = ch[p][m*4+0]*R[i][n] + ch[p][m*4+1]*R[i][3+n] + ch[p][m*4+2]*R[i][6+n];
            else
                val = ch[p][m*4+0]*rel[i][0] + ch[p][m*4+1]*rel[i][1]
                    + ch[p][m*4+2]*rel[i][2] + ch[p][m*4+3];
        }
        if (t < 12) ch[i][t] = val;
        __syncthreads();
    }
    for (int i = t; i < 72; i += 64) {
        int j = i/3, k = i - j*3;
        out[OUT_JPOSED + b*72 + i] = ch[j][k*4+3];
    }
    // A = chain with translation t - R*jrest (fp32 output; k_lbs re-reads it)
    for (int i = t; i < 384; i += 64) {
        int j = i >> 4, e = i & 15, m = e >> 2, n = e & 3;
        float v;
        if (m < 3) {
            if (n < 3) v = ch[j][m*4+n];
            else v = ch[j][m*4+3] - (ch[j][m*4+0]*jrest[j][0] + ch[j][m*4+1]*jrest[j][1]
                                   + ch[j][m*4+2]*jrest[j][2]);
        } else v = (n == 3) ? 1.f : 0.f;
        out[OUT_A + b*384 + i] = v;
    }
}

// ---------------- Kernel D: pose GEMM via MFMA: delta = pf (B x 224) @ posedirs (224 x 20670) ----------------
__global__ __launch_bounds__(256) void k_posegemm(const bf16* __restrict__ wspf,
        const bf16* __restrict__ wspdt, float* __restrict__ dout) {
    const ushort_t* pf  = (const ushort_t*)wspf;
    const ushort_t* pdt = (const ushort_t*)wspdt;
    int lane = threadIdx.x & 63;
    int wave = threadIdx.x >> 6;
    int l15 = lane & 15, quad = lane >> 4;
    int m0 = blockIdx.y * 32;
    int n0 = blockIdx.x * 256 + wave * 64;
    float4v acc[2][4] = {};
    for (int c = 0; c < 7; c++) {
        short8 a[2], bb[4];
#pragma unroll
        for (int mf = 0; mf < 2; mf++)
            a[mf] = *reinterpret_cast<const short8*>(pf + (m0 + mf*16 + l15)*KPAD + c*32 + quad*8);
#pragma unroll
        for (int nf = 0; nf < 4; nf++)
            bb[nf] = *reinterpret_cast<const short8*>(pdt + (n0 + nf*16 + l15)*KPAD + c*32 + quad*8);
#pragma unroll
        for (int mf = 0; mf < 2; mf++)
#pragma unroll
            for (int nf = 0; nf < 4; nf++)
                acc[mf][nf] = __builtin_amdgcn_mfma_f32_16x16x32_bf16(a[mf], bb[nf], acc[mf][nf], 0, 0, 0);
    }
#pragma unroll
    for (int mf = 0; mf < 2; mf++)
#pragma unroll
        for (int nf = 0; nf < 4; nf++) {
            int col = n0 + nf*16 + l15;
            if (col < NCOL) {
#pragma unroll
                for (int r = 0; r < 4; r++) {
                    int row = m0 + mf*16 + quad*4 + r;   // C/D: col=lane&15, row=quad*4+reg
                    dout[row*NCOL + col] = acc[mf][nf][r];
                }
            }
        }
}

// ---------------- Kernel E: v_shaped + LBS + verts (batch-tiled) ----------------
// Each block owns 256 vertices x NB=8 batches. Batch-invariant per-vertex data
// (lbs weights 96B, sd 120B, vt 12B) is loaded into VGPRs ONCE and reused for
// all NB batches -- divides the ~1.6GB of per-dispatch L1/L2 re-reads by NB and
// amortizes addressing VALU. A stays wave-uniform via __restrict__ -> s_load.
__global__ __launch_bounds__(256) void k_lbs(const float* __restrict__ betas,
        const float* __restrict__ sd, const float* __restrict__ vt,
        const float* __restrict__ lbs, const float* __restrict__ Amat,
        float* __restrict__ out) {
    int tid = threadIdx.x;
    int v = blockIdx.x*256 + tid;
    if (v >= VDIM) return;
    int b0 = blockIdx.y * NB;

    // ---- one-time per-vertex loads ----
    float w[24];
    {
        const float4v* W4 = reinterpret_cast<const float4v*>(lbs + v*24);
#pragma unroll
        for (int q = 0; q < 6; q++) {
            float4v x = W4[q];
#pragma unroll
            for (int e = 0; e < 4; e++) w[q*4+e] = x[e];
        }
    }
    float vtv[3];
#pragma unroll
    for (int m = 0; m < 3; m++) vtv[m] = vt[v*3 + m];
    float sdv[30];
#pragma unroll
    for (int i = 0; i < 30; i++) sdv[i] = sd[v*30 + i];

    float* vsh = out + OUT_VSHAPED;

#pragma unroll 1
    for (int bb = 0; bb < NB; bb++) {
        int b = b0 + bb;
        const float* __restrict__ Ab = Amat + (size_t)b*384;   // uniform -> SGPRs

        // T = sum_j w_j * A_j  (SGPR source per fmac)
        float T[12];
#pragma unroll
        for (int e = 0; e < 12; e++) T[e] = 0.f;
#pragma unroll
        for (int j = 0; j < 24; j++) {
#pragma unroll
            for (int e = 0; e < 12; e++)
                T[e] = fmaf(w[j], Ab[j*16 + e], T[e]);
        }

        // v_shaped (betas uniform -> SGPRs; sdv in registers)
        float vs[3];
#pragma unroll
        for (int m = 0; m < 3; m++) {
            float s = vtv[m];
#pragma unroll
            for (int l = 0; l < 10; l++) s += betas[b*10 + l] * sdv[m*10 + l];
            vs[m] = s;
        }

        int base = b*NCOL + v*3;
        float vp0 = vs[0] + vsh[base + 0];
        float vp1 = vs[1] + vsh[base + 1];
        float vp2 = vs[2] + vsh[base + 2];
#pragma unroll
        for (int m = 0; m < 3; m++) {
            float o = T[m*4+3] + T[m*4]*vp0 + T[m*4+1]*vp1 + T[m*4+2]*vp2;
            out[base + m] = o;             // verts at offset 0
            vsh[base + m] = vs[m];         // overwrite scratch with v_shaped
        }
    }
}

extern "C" void kernel_launch(void* const* d_in, const int* in_sizes, int n_in,
                              void* d_out, int out_size, void* d_ws, size_t ws_size,
                              hipStream_t stream) {
    // Bind inputs BY SIZE (robust to dict-order vs alphabetical flattening;
    // the 165360 pair J_regressor/lbs_weights keeps relative order in both).
    const float *betas = nullptr, *pose = nullptr, *vt = nullptr, *sd = nullptr,
                *pd = nullptr, *jreg = nullptr, *lbs = nullptr;
    const int* parents = nullptr;
    for (int i = 0; i < n_in; i++) {
        switch (in_sizes[i]) {
            case 10240:   betas = (const float*)d_in[i]; break;      // (1024,10)
            case 73728:   pose  = (const float*)d_in[i]; break;      // (1024,72)
            case 20670:   vt    = (const float*)d_in[i]; break;      // (1,6890,3)
            case 206700:  sd    = (const float*)d_in[i]; break;      // (6890,3,10)
            case 4278690: pd    = (const float*)d_in[i]; break;      // (207,20670)
            case 24:      parents = (const int*)d_in[i]; break;      // (24,)
            case 165360:                                             // (24,6890)/(6890,24)
                if (!jreg) jreg = (const float*)d_in[i];
                else       lbs  = (const float*)d_in[i];
                break;
            default: break;
        }
    }
    float* out = (float*)d_out;   // reference output dtype is float32
    (void)d_ws; (void)ws_size;

    // Scratch in the verts region of d_out (dead before k_lbs writes verts):
    bf16*  ws_pdt  = (bf16*)(out + SCRF_PDT);
    bf16*  ws_pf   = (bf16*)(out + SCRF_PF);
    float* ws_jtjs = out + SCRF_JTJS;

    k_jtjs<<<24, 256, 0, stream>>>(jreg, vt, sd, ws_jtjs);
    k_transpose<<<dim3(324, 7), 256, 0, stream>>>(pd, ws_pdt);
    k_pose<<<BDIM, 64, 0, stream>>>(betas, pose, parents, ws_jtjs, out, ws_pf);
    k_posegemm<<<dim3(81, 32), 256, 0, stream>>>(ws_pf, ws_pdt, out + OUT_VSHAPED);
    k_lbs<<<dim3(27, BDIM/NB), 256, 0, stream>>>(betas, sd, vt, lbs, out + OUT_A, out);
}

// Round 3
// 341.995 us; speedup vs baseline: 1.3200x; 1.0841x over previous
//
#include <hip/hip_runtime.h>
#include <hip/hip_bf16.h>

#define BDIM 1024
#define VDIM 6890
#define NJ   24
#define NCOL (VDIM*3)   // 20670
#define KPAD 224        // 207 padded to 7*32
#define NPAD 20736      // 108*192 = 81*256 columns, zero-padded for guardless loads
#define NB   8          // batches per k_lbs block (fallback path)

// fp32-element offsets into d_out (float*):
#define OUT_VERTS   0
#define OUT_JPOSED  21166080
#define OUT_JREST   21239808
#define OUT_A       21313536
#define OUT_VSHAPED 21706752

// Fallback-path scratch inside the verts region of d_out (dead before k_lbs
// writes verts). Offsets in fp32 elements; pdt/pf are bf16 arrays.
#define SCRF_PDT    0          // bf16 NPAD*KPAD
#define SCRF_PF     2322432    // bf16 1024*224
#define SCRF_JTJS   2437120    // 792 f32

// Workspace layout (main fused path), byte offsets:
#define WSB_PDT   0u
#define WSB_PF    9289728u                 // NPAD*KPAD*2
#define WSB_JTJS  (9289728u + 458752u)     // + 1024*KPAD*2
#define WS_NEED   (9289728u + 458752u + 3168u)

typedef __hip_bfloat16 bf16;
typedef unsigned short ushort_t;
typedef __attribute__((ext_vector_type(8))) short  short8;
typedef __attribute__((ext_vector_type(4))) float  float4v;

__device__ __forceinline__ bf16  tob(float x) { return __float2bfloat16(x); }

// ---------------- Kernel A: JT/JS precompute (batch-independent) ----------------
__global__ __launch_bounds__(256) void k_jtjs(const float* __restrict__ jreg,
        const float* __restrict__ vt, const float* __restrict__ sd,
        float* __restrict__ jtjs) {
    int j = blockIdx.x;
    int tid = threadIdx.x;
    float acc[33];
#pragma unroll
    for (int i = 0; i < 33; i++) acc[i] = 0.f;
    for (int v = tid; v < VDIM; v += 256) {
        float r = jreg[j*VDIM + v];
#pragma unroll
        for (int m = 0; m < 3; m++) {
            acc[m] += r * vt[v*3+m];
#pragma unroll
            for (int l = 0; l < 10; l++)
                acc[3 + m*10 + l] += r * sd[(v*3+m)*10 + l];
        }
    }
    __shared__ float red[4][33];
    int lane = tid & 63, wid = tid >> 6;
#pragma unroll
    for (int i = 0; i < 33; i++) {
        float x = acc[i];
        for (int off = 32; off > 0; off >>= 1) x += __shfl_down(x, off);
        if (lane == 0) red[wid][i] = x;
    }
    __syncthreads();
    if (tid < 33)
        jtjs[j*33 + tid] = red[0][tid] + red[1][tid] + red[2][tid] + red[3][tid];
}

// ---------------- Kernel PT: transpose posedirs f32 (207 x 20670) -> bf16 (NPAD x 224) ----------------
__global__ __launch_bounds__(256) void k_transpose(const float* __restrict__ pd,
        bf16* __restrict__ pdt) {
    __shared__ bf16 tile[32][65];
    int nt = blockIdx.x * 64;
    int kt = blockIdx.y * 32;
    int t = threadIdx.x;
    for (int i = t; i < 32*64; i += 256) {
        int kk = i >> 6, nn = i & 63;
        int k = kt + kk, n = nt + nn;
        float v = 0.f;
        if (k < 207 && n < NCOL) v = pd[k*NCOL + n];
        tile[kk][nn] = tob(v);
    }
    __syncthreads();
    for (int i = t; i < 32*64; i += 256) {
        int kk = i & 31, nn = i >> 5;
        pdt[(nt + nn)*KPAD + kt + kk] = tile[kk][nn];
    }
}

// ---------------- Kernel B: per-batch pose (Rodrigues, chain, A, J_rest, J_posed) ----------------
__global__ __launch_bounds__(64) void k_pose(const float* __restrict__ betas,
        const float* __restrict__ pose, const int* __restrict__ parents,
        const float* __restrict__ jtjs, float* __restrict__ out,
        bf16* __restrict__ wspf) {
    int b = blockIdx.x, t = threadIdx.x;
    __shared__ float R[24][9];
    __shared__ float jrest[24][3];
    __shared__ float rel[24][3];
    __shared__ float ch[24][12];
    __shared__ int par[24];
    if (t < 24) {
        par[t] = parents[t];
        float rx = pose[b*72 + t*3 + 0];
        float ry = pose[b*72 + t*3 + 1];
        float rz = pose[b*72 + t*3 + 2];
        float ax = rx + 1e-8f, ay = ry + 1e-8f, az = rz + 1e-8f;
        float angle = sqrtf(ax*ax + ay*ay + az*az);
        float inv = 1.0f / angle;               // axis = original r / angle (ref semantics)
        float kx = rx*inv, ky = ry*inv, kz = rz*inv;
        float s = sinf(angle), c = cosf(angle);
        float t1 = 1.0f - c;
        float q = kx*kx + ky*ky + kz*kz;        // K^2 = kk^T - (k.k) I
        R[t][0] = 1.f + t1*(kx*kx - q);
        R[t][1] = -s*kz + t1*kx*ky;
        R[t][2] =  s*ky + t1*kx*kz;
        R[t][3] =  s*kz + t1*kx*ky;
        R[t][4] = 1.f + t1*(ky*ky - q);
        R[t][5] = -s*kx + t1*ky*kz;
        R[t][6] = -s*ky + t1*kx*kz;
        R[t][7] =  s*kx + t1*ky*kz;
        R[t][8] = 1.f + t1*(kz*kz - q);
    }
    __syncthreads();
    // pose_feature -> scratch (bf16, zero-padded to KPAD)
    for (int i = t; i < KPAD; i += 64) {
        float pf = 0.f;
        if (i < 207) {
            int j = i/9 + 1, e = i - (j-1)*9;
            pf = R[j][e] - ((e == 0 || e == 4 || e == 8) ? 1.f : 0.f);
        }
        wspf[b*KPAD + i] = tob(pf);
    }
    // J_rest = JT + JS . betas   (64 threads -> strided loop over 72)
    for (int i = t; i < 72; i += 64) {
        int j = i/3, k = i - j*3;
        const float* JJ = &jtjs[j*33];
        float s = JJ[k];
#pragma unroll
        for (int l = 0; l < 10; l++) s += JJ[3 + k*10 + l] * betas[b*10 + l];
        jrest[j][k] = s;
        out[OUT_JREST + b*72 + i] = s;
    }
    __syncthreads();
    for (int i = t; i < 72; i += 64) {
        int j = i/3, k = i - j*3;
        rel[j][k] = jrest[j][k] - (j > 0 ? jrest[par[j]][k] : 0.f);
    }
    __syncthreads();
    if (t < 12) {
        int m = t >> 2, n = t & 3;
        ch[0][t] = (n < 3) ? R[0][m*3+n] : rel[0][m];
    }
    __syncthreads();
    for (int i = 1; i < 24; i++) {
        float val = 0.f;
        if (t < 12) {
            int m = t >> 2, n = t & 3;
            int p = par[i];                      // p < i: no overlap with ch[i] write
            if (n < 3)
                val = ch[p][m*4+0]*R[i][n] + ch[p][m*4+1]*R[i][3+n] + ch[p][m*4+2]*R[i][6+n];
            else
                val = ch[p][m*4+0]*rel[i][0] + ch[p][m*4+1]*rel[i][1]
                    + ch[p][m*4+2]*rel[i][2] + ch[p][m*4+3];
        }
        if (t < 12) ch[i][t] = val;
        __syncthreads();
    }
    for (int i = t; i < 72; i += 64) {
        int j = i/3, k = i - j*3;
        out[OUT_JPOSED + b*72 + i] = ch[j][k*4+3];
    }
    // A = chain with translation t - R*jrest (fp32 output; consumers re-read it)
    for (int i = t; i < 384; i += 64) {
        int j = i >> 4, e = i & 15, m = e >> 2, n = e & 3;
        float v;
        if (m < 3) {
            if (n < 3) v = ch[j][m*4+n];
            else v = ch[j][m*4+3] - (ch[j][m*4+0]*jrest[j][0] + ch[j][m*4+1]*jrest[j][1]
                                   + ch[j][m*4+2]*jrest[j][2]);
        } else v = (n == 3) ? 1.f : 0.f;
        out[OUT_A + b*384 + i] = v;
    }
}

// ---------------- Kernel F (main path): fused pose-GEMM + LBS ----------------
// Tile: 32 batches x 64 vertices (192 delta cols). Phase 1: MFMA computes the
// delta tile (identical MFMA sequence/order to k_posegemm -> bit-identical
// values) and parks it in LDS (stride 196 words: write path 2-way conflict =
// free, read path stride-3 = free). Phase 2: lane=vertex, wave=8-batch group;
// batch rebuilt via readfirstlane so A/betas stay SGPR s_loads. Eliminates the
// 169 MB fp32 delta round-trip through HBM.
__global__ __launch_bounds__(256) void k_gemmlbs(const bf16* __restrict__ wspf,
        const bf16* __restrict__ wspdt, const float* __restrict__ betas,
        const float* __restrict__ sd, const float* __restrict__ vt,
        const float* __restrict__ lbs, const float* __restrict__ Amat,
        float* __restrict__ out) {
    __shared__ float dtile[32][196];
    const ushort_t* pf  = (const ushort_t*)wspf;
    const ushort_t* pdt = (const ushort_t*)wspdt;
    int tid  = threadIdx.x;
    int lane = tid & 63, wave = tid >> 6;
    int l15 = lane & 15, quad = lane >> 4;
    int m0 = blockIdx.y * 32;          // batch base
    int v0 = blockIdx.x * 64;          // vertex base
    int cb = wave * 48;                // wave's col base within tile
    int colb = v0*3 + cb;              // global col base (max 20735 < NPAD)

    // ---- Phase 1: GEMM (delta tile) ----
    float4v acc[2][3] = {};
    for (int c = 0; c < 7; c++) {
        short8 a[2], bb[3];
#pragma unroll
        for (int mf = 0; mf < 2; mf++)
            a[mf] = *reinterpret_cast<const short8*>(pf + (m0 + mf*16 + l15)*KPAD + c*32 + quad*8);
#pragma unroll
        for (int nf = 0; nf < 3; nf++)
            bb[nf] = *reinterpret_cast<const short8*>(pdt + (colb + nf*16 + l15)*KPAD + c*32 + quad*8);
#pragma unroll
        for (int mf = 0; mf < 2; mf++)
#pragma unroll
            for (int nf = 0; nf < 3; nf++)
                acc[mf][nf] = __builtin_amdgcn_mfma_f32_16x16x32_bf16(a[mf], bb[nf], acc[mf][nf], 0, 0, 0);
    }
#pragma unroll
    for (int mf = 0; mf < 2; mf++)
#pragma unroll
        for (int nf = 0; nf < 3; nf++)
#pragma unroll
            for (int r = 0; r < 4; r++)
                dtile[mf*16 + quad*4 + r][cb + nf*16 + l15] = acc[mf][nf][r];
    __syncthreads();

    // ---- Phase 2: LBS (lane = vertex, wave = 8-batch group) ----
    int v = v0 + lane;
    if (v >= VDIM) return;

    float w[24];
    {
        const float4v* W4 = reinterpret_cast<const float4v*>(lbs + v*24);
#pragma unroll
        for (int q = 0; q < 6; q++) {
            float4v x = W4[q];
#pragma unroll
            for (int e = 0; e < 4; e++) w[q*4+e] = x[e];
        }
    }
    float vtv[3];
#pragma unroll
    for (int m = 0; m < 3; m++) vtv[m] = vt[v*3 + m];
    float sdv[30];
#pragma unroll
    for (int i = 0; i < 30; i++) sdv[i] = sd[v*30 + i];

    int wv = __builtin_amdgcn_readfirstlane(wave);   // provably uniform batch group
    float* vsh = out + OUT_VSHAPED;

#pragma unroll 1
    for (int bb2 = 0; bb2 < 8; bb2++) {
        int b  = m0 + wv*8 + bb2;                    // scalar
        int bl = wv*8 + bb2;                         // local batch row in dtile
        const float* __restrict__ Ab = Amat + (size_t)b*384;   // uniform -> s_load

        float T[12];
#pragma unroll
        for (int e = 0; e < 12; e++) T[e] = 0.f;
#pragma unroll
        for (int j = 0; j < 24; j++) {
#pragma unroll
            for (int e = 0; e < 12; e++)
                T[e] = fmaf(w[j], Ab[j*16 + e], T[e]);
        }

        float vs[3];
#pragma unroll
        for (int m = 0; m < 3; m++) {
            float s = vtv[m];
#pragma unroll
            for (int l = 0; l < 10; l++) s += betas[b*10 + l] * sdv[m*10 + l];
            vs[m] = s;
        }

        float vp0 = vs[0] + dtile[bl][lane*3 + 0];
        float vp1 = vs[1] + dtile[bl][lane*3 + 1];
        float vp2 = vs[2] + dtile[bl][lane*3 + 2];
        int base = b*NCOL + v*3;
#pragma unroll
        for (int m = 0; m < 3; m++) {
            float o = T[m*4+3] + T[m*4]*vp0 + T[m*4+1]*vp1 + T[m*4+2]*vp2;
            out[base + m]  = o;            // verts
            vsh[base + m]  = vs[m];        // v_shaped
        }
    }
}

// ---------------- Fallback kernels (ws too small): R1 pipeline ----------------
__global__ __launch_bounds__(256) void k_posegemm(const bf16* __restrict__ wspf,
        const bf16* __restrict__ wspdt, float* __restrict__ dout) {
    const ushort_t* pf  = (const ushort_t*)wspf;
    const ushort_t* pdt = (const ushort_t*)wspdt;
    int lane = threadIdx.x & 63;
    int wave = threadIdx.x >> 6;
    int l15 = lane & 15, quad = lane >> 4;
    int m0 = blockIdx.y * 32;
    int n0 = blockIdx.x * 256 + wave * 64;
    float4v acc[2][4] = {};
    for (int c = 0; c < 7; c++) {
        short8 a[2], bb[4];
#pragma unroll
        for (int mf = 0; mf < 2; mf++)
            a[mf] = *reinterpret_cast<const short8*>(pf + (m0 + mf*16 + l15)*KPAD + c*32 + quad*8);
#pragma unroll
        for (int nf = 0; nf < 4; nf++)
            bb[nf] = *reinterpret_cast<const short8*>(pdt + (n0 + nf*16 + l15)*KPAD + c*32 + quad*8);
#pragma unroll
        for (int mf = 0; mf < 2; mf++)
#pragma unroll
            for (int nf = 0; nf < 4; nf++)
                acc[mf][nf] = __builtin_amdgcn_mfma_f32_16x16x32_bf16(a[mf], bb[nf], acc[mf][nf], 0, 0, 0);
    }
#pragma unroll
    for (int mf = 0; mf < 2; mf++)
#pragma unroll
        for (int nf = 0; nf < 4; nf++) {
            int col = n0 + nf*16 + l15;
            if (col < NCOL) {
#pragma unroll
                for (int r = 0; r < 4; r++) {
                    int row = m0 + mf*16 + quad*4 + r;
                    dout[row*NCOL + col] = acc[mf][nf][r];
                }
            }
        }
}

__global__ __launch_bounds__(256) void k_lbs(const float* __restrict__ betas,
        const float* __restrict__ sd, const float* __restrict__ vt,
        const float* __restrict__ lbs, const float* __restrict__ Amat,
        float* __restrict__ out) {
    int tid = threadIdx.x;
    int v = blockIdx.x*256 + tid;
    if (v >= VDIM) return;
    int b0 = blockIdx.y * NB;
    float w[24];
    {
        const float4v* W4 = reinterpret_cast<const float4v*>(lbs + v*24);
#pragma unroll
        for (int q = 0; q < 6; q++) {
            float4v x = W4[q];
#pragma unroll
            for (int e = 0; e < 4; e++) w[q*4+e] = x[e];
        }
    }
    float vtv[3];
#pragma unroll
    for (int m = 0; m < 3; m++) vtv[m] = vt[v*3 + m];
    float sdv[30];
#pragma unroll
    for (int i = 0; i < 30; i++) sdv[i] = sd[v*30 + i];
    float* vsh = out + OUT_VSHAPED;
#pragma unroll 1
    for (int bb = 0; bb < NB; bb++) {
        int b = b0 + bb;
        const float* __restrict__ Ab = Amat + (size_t)b*384;
        float T[12];
#pragma unroll
        for (int e = 0; e < 12; e++) T[e] = 0.f;
#pragma unroll
        for (int j = 0; j < 24; j++) {
#pragma unroll
            for (int e = 0; e < 12; e++)
                T[e] = fmaf(w[j], Ab[j*16 + e], T[e]);
        }
        float vs[3];
#pragma unroll
        for (int m = 0; m < 3; m++) {
            float s = vtv[m];
#pragma unroll
            for (int l = 0; l < 10; l++) s += betas[b*10 + l] * sdv[m*10 + l];
            vs[m] = s;
        }
        int base = b*NCOL + v*3;
        float vp0 = vs[0] + vsh[base + 0];
        float vp1 = vs[1] + vsh[base + 1];
        float vp2 = vs[2] + vsh[base + 2];
#pragma unroll
        for (int m = 0; m < 3; m++) {
            float o = T[m*4+3] + T[m*4]*vp0 + T[m*4+1]*vp1 + T[m*4+2]*vp2;
            out[base + m] = o;
            vsh[base + m] = vs[m];
        }
    }
}

extern "C" void kernel_launch(void* const* d_in, const int* in_sizes, int n_in,
                              void* d_out, int out_size, void* d_ws, size_t ws_size,
                              hipStream_t stream) {
    const float *betas = nullptr, *pose = nullptr, *vt = nullptr, *sd = nullptr,
                *pd = nullptr, *jreg = nullptr, *lbs = nullptr;
    const int* parents = nullptr;
    for (int i = 0; i < n_in; i++) {
        switch (in_sizes[i]) {
            case 10240:   betas = (const float*)d_in[i]; break;      // (1024,10)
            case 73728:   pose  = (const float*)d_in[i]; break;      // (1024,72)
            case 20670:   vt    = (const float*)d_in[i]; break;      // (1,6890,3)
            case 206700:  sd    = (const float*)d_in[i]; break;      // (6890,3,10)
            case 4278690: pd    = (const float*)d_in[i]; break;      // (207,20670)
            case 24:      parents = (const int*)d_in[i]; break;      // (24,)
            case 165360:                                             // (24,6890)/(6890,24)
                if (!jreg) jreg = (const float*)d_in[i];
                else       lbs  = (const float*)d_in[i];
                break;
            default: break;
        }
    }
    float* out = (float*)d_out;
    if (d_ws && ws_size >= (size_t)WS_NEED) {
        // Main path: scratch in workspace; fused GEMM+LBS (no delta round-trip).
        bf16*  ws_pdt  = (bf16*)((char*)d_ws + WSB_PDT);
        bf16*  ws_pf   = (bf16*)((char*)d_ws + WSB_PF);
        float* ws_jtjs = (float*)((char*)d_ws + WSB_JTJS);
        k_jtjs<<<24, 256, 0, stream>>>(jreg, vt, sd, ws_jtjs);
        k_transpose<<<dim3(324, 7), 256, 0, stream>>>(pd, ws_pdt);
        k_pose<<<BDIM, 64, 0, stream>>>(betas, pose, parents, ws_jtjs, out, ws_pf);
        k_gemmlbs<<<dim3(108, 32), 256, 0, stream>>>(ws_pf, ws_pdt, betas, sd, vt, lbs,
                                                     out + OUT_A, out);
    } else {
        // Fallback (R1 pipeline): scratch inside the verts region of d_out.
        bf16*  ws_pdt  = (bf16*)(out + SCRF_PDT);
        bf16*  ws_pf   = (bf16*)(out + SCRF_PF);
        float* ws_jtjs = out + SCRF_JTJS;
        k_jtjs<<<24, 256, 0, stream>>>(jreg, vt, sd, ws_jtjs);
        k_transpose<<<dim3(324, 7), 256, 0, stream>>>(pd, ws_pdt);
        k_pose<<<BDIM, 64, 0, stream>>>(betas, pose, parents, ws_jtjs, out, ws_pf);
        k_posegemm<<<dim3(81, 32), 256, 0, stream>>>(ws_pf, ws_pdt, out + OUT_VSHAPED);
        k_lbs<<<dim3(27, BDIM/NB), 256, 0, stream>>>(betas, sd, vt, lbs, out + OUT_A, out);
    }
}

// Round 4
// 300.231 us; speedup vs baseline: 1.5036x; 1.1391x over previous
//
#include <hip/hip_runtime.h>
#include <hip/hip_bf16.h>

#define BDIM 1024
#define VDIM 6890
#define NJ   24
#define NCOL (VDIM*3)   // 20670
#define KPAD 224        // 207 padded to 7*32
#define NPAD 20736      // 108*192 = 81*256 columns, zero-padded for guardless loads
#define NB   8          // batches per k_lbs block (fallback path)
#define VPAD 6912       // 108*64 vertices, zero-padded for W fragments

// fp32-element offsets into d_out (float*):
#define OUT_VERTS   0
#define OUT_JPOSED  21166080
#define OUT_JREST   21239808
#define OUT_A       21313536
#define OUT_VSHAPED 21706752

// Fallback-path scratch inside the verts region of d_out (dead before k_lbs
// writes verts). Offsets in fp32 elements; pdt/pf are bf16 arrays.
#define SCRF_PDT    0          // bf16 NPAD*KPAD
#define SCRF_PF     2322432    // bf16 1024*224
#define SCRF_JTJS   2437120    // 792 f32

// Workspace layout (main fused path), byte offsets:
#define WSB_PDT   0u
#define WSB_PF    9289728u                    // NPAD*KPAD*2
#define WSB_JTJS  9748480u                    // + 1024*KPAD*2
#define WSB_WHI   9752064u                    // jtjs 3168 B, aligned up
#define WSB_WLO   10194432u                   // + VPAD*32*2
#define WS_NEED   10636800u                   // + VPAD*32*2

typedef __hip_bfloat16 bf16;
typedef unsigned short ushort_t;
typedef __attribute__((ext_vector_type(8))) short  short8;
typedef __attribute__((ext_vector_type(4))) float  float4v;

__device__ __forceinline__ bf16  tob(float x) { return __float2bfloat16(x); }

// RNE float->bf16 bit helpers (self-consistent hi/lo split; finite inputs only)
__device__ __forceinline__ ushort_t bf16_rne(float x) {
    unsigned u = __builtin_bit_cast(unsigned, x);
    unsigned r = (u + 0x7FFFu + ((u >> 16) & 1u)) >> 16;
    return (ushort_t)r;
}
__device__ __forceinline__ float bf16_to_f(ushort_t h) {
    unsigned u = ((unsigned)h) << 16;
    return __builtin_bit_cast(float, u);
}

// ---------------- Kernel A: JT/JS precompute (batch-independent) ----------------
__global__ __launch_bounds__(256) void k_jtjs(const float* __restrict__ jreg,
        const float* __restrict__ vt, const float* __restrict__ sd,
        float* __restrict__ jtjs) {
    int j = blockIdx.x;
    int tid = threadIdx.x;
    float acc[33];
#pragma unroll
    for (int i = 0; i < 33; i++) acc[i] = 0.f;
    for (int v = tid; v < VDIM; v += 256) {
        float r = jreg[j*VDIM + v];
#pragma unroll
        for (int m = 0; m < 3; m++) {
            acc[m] += r * vt[v*3+m];
#pragma unroll
            for (int l = 0; l < 10; l++)
                acc[3 + m*10 + l] += r * sd[(v*3+m)*10 + l];
        }
    }
    __shared__ float red[4][33];
    int lane = tid & 63, wid = tid >> 6;
#pragma unroll
    for (int i = 0; i < 33; i++) {
        float x = acc[i];
        for (int off = 32; off > 0; off >>= 1) x += __shfl_down(x, off);
        if (lane == 0) red[wid][i] = x;
    }
    __syncthreads();
    if (tid < 33)
        jtjs[j*33 + tid] = red[0][tid] + red[1][tid] + red[2][tid] + red[3][tid];
}

// ---------------- Kernel PT: transpose posedirs f32 (207 x 20670) -> bf16 (NPAD x 224) ----------------
__global__ __launch_bounds__(256) void k_transpose(const float* __restrict__ pd,
        bf16* __restrict__ pdt) {
    __shared__ bf16 tile[32][65];
    int nt = blockIdx.x * 64;
    int kt = blockIdx.y * 32;
    int t = threadIdx.x;
    for (int i = t; i < 32*64; i += 256) {
        int kk = i >> 6, nn = i & 63;
        int k = kt + kk, n = nt + nn;
        float v = 0.f;
        if (k < 207 && n < NCOL) v = pd[k*NCOL + n];
        tile[kk][nn] = tob(v);
    }
    __syncthreads();
    for (int i = t; i < 32*64; i += 256) {
        int kk = i & 31, nn = i >> 5;
        pdt[(nt + nn)*KPAD + kt + kk] = tile[kk][nn];
    }
}

// ---------------- Kernel W: pack lbs_weights -> bf16 hi/lo fragments ----------------
// W_pack[v][k], v < VPAD (zero-pad), k < 32 (24 joints + zero-pad). hi+lo
// reconstructs fp32 weight to ~2^-18 relative.
__global__ __launch_bounds__(256) void k_wpack(const float* __restrict__ lbs,
        ushort_t* __restrict__ whi, ushort_t* __restrict__ wlo) {
    int idx = blockIdx.x*256 + threadIdx.x;
    if (idx >= VPAD*32) return;
    int v = idx >> 5, j = idx & 31;
    float x = (v < VDIM && j < 24) ? lbs[v*24 + j] : 0.f;
    ushort_t h = bf16_rne(x);
    whi[idx] = h;
    wlo[idx] = bf16_rne(x - bf16_to_f(h));
}

// ---------------- Kernel B: per-batch pose (Rodrigues, chain, A, J_rest, J_posed) ----------------
__global__ __launch_bounds__(64) void k_pose(const float* __restrict__ betas,
        const float* __restrict__ pose, const int* __restrict__ parents,
        const float* __restrict__ jtjs, float* __restrict__ out,
        bf16* __restrict__ wspf) {
    int b = blockIdx.x, t = threadIdx.x;
    __shared__ float R[24][9];
    __shared__ float jrest[24][3];
    __shared__ float rel[24][3];
    __shared__ float ch[24][12];
    __shared__ int par[24];
    if (t < 24) {
        par[t] = parents[t];
        float rx = pose[b*72 + t*3 + 0];
        float ry = pose[b*72 + t*3 + 1];
        float rz = pose[b*72 + t*3 + 2];
        float ax = rx + 1e-8f, ay = ry + 1e-8f, az = rz + 1e-8f;
        float angle = sqrtf(ax*ax + ay*ay + az*az);
        float inv = 1.0f / angle;               // axis = original r / angle (ref semantics)
        float kx = rx*inv, ky = ry*inv, kz = rz*inv;
        float s = sinf(angle), c = cosf(angle);
        float t1 = 1.0f - c;
        float q = kx*kx + ky*ky + kz*kz;        // K^2 = kk^T - (k.k) I
        R[t][0] = 1.f + t1*(kx*kx - q);
        R[t][1] = -s*kz + t1*kx*ky;
        R[t][2] =  s*ky + t1*kx*kz;
        R[t][3] =  s*kz + t1*kx*ky;
        R[t][4] = 1.f + t1*(ky*ky - q);
        R[t][5] = -s*kx + t1*ky*kz;
        R[t][6] = -s*ky + t1*kx*kz;
        R[t][7] =  s*kx + t1*ky*kz;
        R[t][8] = 1.f + t1*(kz*kz - q);
    }
    __syncthreads();
    // pose_feature -> scratch (bf16, zero-padded to KPAD)
    for (int i = t; i < KPAD; i += 64) {
        float pf = 0.f;
        if (i < 207) {
            int j = i/9 + 1, e = i - (j-1)*9;
            pf = R[j][e] - ((e == 0 || e == 4 || e == 8) ? 1.f : 0.f);
        }
        wspf[b*KPAD + i] = tob(pf);
    }
    // J_rest = JT + JS . betas   (64 threads -> strided loop over 72)
    for (int i = t; i < 72; i += 64) {
        int j = i/3, k = i - j*3;
        const float* JJ = &jtjs[j*33];
        float s = JJ[k];
#pragma unroll
        for (int l = 0; l < 10; l++) s += JJ[3 + k*10 + l] * betas[b*10 + l];
        jrest[j][k] = s;
        out[OUT_JREST + b*72 + i] = s;
    }
    __syncthreads();
    for (int i = t; i < 72; i += 64) {
        int j = i/3, k = i - j*3;
        rel[j][k] = jrest[j][k] - (j > 0 ? jrest[par[j]][k] : 0.f);
    }
    __syncthreads();
    if (t < 12) {
        int m = t >> 2, n = t & 3;
        ch[0][t] = (n < 3) ? R[0][m*3+n] : rel[0][m];
    }
    __syncthreads();
    for (int i = 1; i < 24; i++) {
        float val = 0.f;
        if (t < 12) {
            int m = t >> 2, n = t & 3;
            int p = par[i];                      // p < i: no overlap with ch[i] write
            if (n < 3)
                val = ch[p][m*4+0]*R[i][n] + ch[p][m*4+1]*R[i][3+n] + ch[p][m*4+2]*R[i][6+n];
            else
                val = ch[p][m*4+0]*rel[i][0] + ch[p][m*4+1]*rel[i][1]
                    + ch[p][m*4+2]*rel[i][2] + ch[p][m*4+3];
        }
        if (t < 12) ch[i][t] = val;
        __syncthreads();
    }
    for (int i = t; i < 72; i += 64) {
        int j = i/3, k = i - j*3;
        out[OUT_JPOSED + b*72 + i] = ch[j][k*4+3];
    }
    // A = chain with translation t - R*jrest (fp32 output; consumers re-read it)
    for (int i = t; i < 384; i += 64) {
        int j = i >> 4, e = i & 15, m = e >> 2, n = e & 3;
        float v;
        if (m < 3) {
            if (n < 3) v = ch[j][m*4+n];
            else v = ch[j][m*4+3] - (ch[j][m*4+0]*jrest[j][0] + ch[j][m*4+1]*jrest[j][1]
                                   + ch[j][m*4+2]*jrest[j][2]);
        } else v = (n == 3) ? 1.f : 0.f;
        out[OUT_A + b*384 + i] = v;
    }
}

// ---------------- Kernel F (main path): fused pose-GEMM + LBS, all-MFMA ----------------
// Tile: 32 batches x 64 vertices. Phase 1: delta tile via MFMA (identical to
// before -> bit-identical) parked in LDS. Phase 2 (lane=vertex): vp = vs+delta
// written back IN-PLACE into dtile; vsh stored. Phase 3: T = W@A moved to the
// matrix pipe as a 3-term bf16-split MFMA (err ~1e-5, invisible vs the 0.0156
// bf16 delta GEMM): D-layout col=vertex(l15), row=e(quad*4+r) -> lane (quad=m,
// l15) holds T-row m for its vertex and applies it to vp from LDS (broadcast
// across quads = conflict-free). Removes the 288-fmac x8 VALU loop and the
// per-batch 1.2KB s_load chain that bounded R2's version at 137 us.
__global__ __launch_bounds__(256) void k_gemmlbs(const bf16* __restrict__ wspf,
        const bf16* __restrict__ wspdt, const float* __restrict__ betas,
        const float* __restrict__ sd, const float* __restrict__ vt,
        const ushort_t* __restrict__ whi, const ushort_t* __restrict__ wlo,
        const float* __restrict__ Amat, float* __restrict__ out) {
    __shared__ float dtile[32][196];
    const ushort_t* pf  = (const ushort_t*)wspf;
    const ushort_t* pdt = (const ushort_t*)wspdt;
    int tid  = threadIdx.x;
    int lane = tid & 63, wave = tid >> 6;
    int l15 = lane & 15, quad = lane >> 4;
    int m0 = blockIdx.y * 32;          // batch base
    int v0 = blockIdx.x * 64;          // vertex base
    int cb = wave * 48;                // wave's col base within tile
    int colb = v0*3 + cb;              // global col base (max 20735 < NPAD)

    // ---- Phase 1: pose-delta GEMM (bf16 K=224) ----
    {
        float4v acc[2][3] = {};
        for (int c = 0; c < 7; c++) {
            short8 a[2], bb[3];
#pragma unroll
            for (int mf = 0; mf < 2; mf++)
                a[mf] = *reinterpret_cast<const short8*>(pf + (m0 + mf*16 + l15)*KPAD + c*32 + quad*8);
#pragma unroll
            for (int nf = 0; nf < 3; nf++)
                bb[nf] = *reinterpret_cast<const short8*>(pdt + (colb + nf*16 + l15)*KPAD + c*32 + quad*8);
#pragma unroll
            for (int mf = 0; mf < 2; mf++)
#pragma unroll
                for (int nf = 0; nf < 3; nf++)
                    acc[mf][nf] = __builtin_amdgcn_mfma_f32_16x16x32_bf16(a[mf], bb[nf], acc[mf][nf], 0, 0, 0);
        }
#pragma unroll
        for (int mf = 0; mf < 2; mf++)
#pragma unroll
            for (int nf = 0; nf < 3; nf++)
#pragma unroll
                for (int r = 0; r < 4; r++)
                    dtile[mf*16 + quad*4 + r][cb + nf*16 + l15] = acc[mf][nf][r];
    }
    __syncthreads();

    // ---- Phase 2: vs, vp in-place, vsh (lane = vertex) ----
    int wv = __builtin_amdgcn_readfirstlane(wave);   // provably uniform batch group
    int v = v0 + lane;
    float* vsh = out + OUT_VSHAPED;
    if (v < VDIM) {
        float vtv[3];
#pragma unroll
        for (int m = 0; m < 3; m++) vtv[m] = vt[v*3 + m];
        float sdv[30];
#pragma unroll
        for (int i = 0; i < 30; i++) sdv[i] = sd[v*30 + i];
#pragma unroll 1
        for (int bb2 = 0; bb2 < 8; bb2++) {
            int b  = m0 + wv*8 + bb2;                // scalar
            int bl = wv*8 + bb2;
            float vs[3];
#pragma unroll
            for (int m = 0; m < 3; m++) {
                float s = vtv[m];
#pragma unroll
                for (int l = 0; l < 10; l++) s += betas[b*10 + l] * sdv[m*10 + l];
                vs[m] = s;
            }
            int base = b*NCOL + v*3;
#pragma unroll
            for (int n = 0; n < 3; n++) {
                float d = dtile[bl][lane*3 + n];
                dtile[bl][lane*3 + n] = vs[n] + d;   // vp, in-place
                vsh[base + n] = vs[n];
            }
        }
    }
    __syncthreads();

    // ---- Phase 3: T via 3-split MFMA + apply ----
    // B-operand: W^T (col=vertex l15, k=joint quad*8+i), loaded once.
    short8 bhi[4], blo[4];
#pragma unroll
    for (int nf = 0; nf < 4; nf++) {
        int vv = v0 + nf*16 + l15;                   // < VPAD, padded
        bhi[nf] = *reinterpret_cast<const short8*>(whi + vv*32 + quad*8);
        blo[nf] = *reinterpret_cast<const short8*>(wlo + vv*32 + quad*8);
    }
    bool aval = (quad < 3) && (l15 < 12);            // A row=e(l15)<12, k=j<24
#pragma unroll 1
    for (int bb2 = 0; bb2 < 8; bb2++) {
        int b  = m0 + wv*8 + bb2;
        int bl = wv*8 + bb2;
        float af[8];
#pragma unroll
        for (int i = 0; i < 8; i++)
            af[i] = aval ? Amat[(size_t)b*384 + (quad*8 + i)*16 + l15] : 0.f;
        short8 ahi, alo;
#pragma unroll
        for (int i = 0; i < 8; i++) {
            ushort_t h = bf16_rne(af[i]);
            ahi[i] = (short)h;
            alo[i] = (short)bf16_rne(af[i] - bf16_to_f(h));
        }
#pragma unroll
        for (int nf = 0; nf < 4; nf++) {
            float4v acc = {};
            acc = __builtin_amdgcn_mfma_f32_16x16x32_bf16(ahi, bhi[nf], acc, 0, 0, 0);
            acc = __builtin_amdgcn_mfma_f32_16x16x32_bf16(alo, bhi[nf], acc, 0, 0, 0);
            acc = __builtin_amdgcn_mfma_f32_16x16x32_bf16(ahi, blo[nf], acc, 0, 0, 0);
            int vl = nf*16 + l15;
            float vp0 = dtile[bl][vl*3 + 0];
            float vp1 = dtile[bl][vl*3 + 1];
            float vp2 = dtile[bl][vl*3 + 2];
            if (quad < 3 && v0 + vl < VDIM) {
                // acc[r]: row e = quad*4+r -> T[m=quad][n=r]
                float o = acc[3] + acc[0]*vp0 + acc[1]*vp1 + acc[2]*vp2;
                out[(size_t)b*NCOL + (v0 + vl)*3 + quad] = o;
            }
        }
    }
}

// ---------------- Fallback kernels (ws too small): R1 pipeline ----------------
__global__ __launch_bounds__(256) void k_posegemm(const bf16* __restrict__ wspf,
        const bf16* __restrict__ wspdt, float* __restrict__ dout) {
    const ushort_t* pf  = (const ushort_t*)wspf;
    const ushort_t* pdt = (const ushort_t*)wspdt;
    int lane = threadIdx.x & 63;
    int wave = threadIdx.x >> 6;
    int l15 = lane & 15, quad = lane >> 4;
    int m0 = blockIdx.y * 32;
    int n0 = blockIdx.x * 256 + wave * 64;
    float4v acc[2][4] = {};
    for (int c = 0; c < 7; c++) {
        short8 a[2], bb[4];
#pragma unroll
        for (int mf = 0; mf < 2; mf++)
            a[mf] = *reinterpret_cast<const short8*>(pf + (m0 + mf*16 + l15)*KPAD + c*32 + quad*8);
#pragma unroll
        for (int nf = 0; nf < 4; nf++)
            bb[nf] = *reinterpret_cast<const short8*>(pdt + (n0 + nf*16 + l15)*KPAD + c*32 + quad*8);
#pragma unroll
        for (int mf = 0; mf < 2; mf++)
#pragma unroll
            for (int nf = 0; nf < 4; nf++)
                acc[mf][nf] = __builtin_amdgcn_mfma_f32_16x16x32_bf16(a[mf], bb[nf], acc[mf][nf], 0, 0, 0);
    }
#pragma unroll
    for (int mf = 0; mf < 2; mf++)
#pragma unroll
        for (int nf = 0; nf < 4; nf++) {
            int col = n0 + nf*16 + l15;
            if (col < NCOL) {
#pragma unroll
                for (int r = 0; r < 4; r++) {
                    int row = m0 + mf*16 + quad*4 + r;
                    dout[row*NCOL + col] = acc[mf][nf][r];
                }
            }
        }
}

__global__ __launch_bounds__(256) void k_lbs(const float* __restrict__ betas,
        const float* __restrict__ sd, const float* __restrict__ vt,
        const float* __restrict__ lbs, const float* __restrict__ Amat,
        float* __restrict__ out) {
    int tid = threadIdx.x;
    int v = blockIdx.x*256 + tid;
    if (v >= VDIM) return;
    int b0 = blockIdx.y * NB;
    float w[24];
    {
        const float4v* W4 = reinterpret_cast<const float4v*>(lbs + v*24);
#pragma unroll
        for (int q = 0; q < 6; q++) {
            float4v x = W4[q];
#pragma unroll
            for (int e = 0; e < 4; e++) w[q*4+e] = x[e];
        }
    }
    float vtv[3];
#pragma unroll
    for (int m = 0; m < 3; m++) vtv[m] = vt[v*3 + m];
    float sdv[30];
#pragma unroll
    for (int i = 0; i < 30; i++) sdv[i] = sd[v*30 + i];
    float* vsh = out + OUT_VSHAPED;
#pragma unroll 1
    for (int bb = 0; bb < NB; bb++) {
        int b = b0 + bb;
        const float* __restrict__ Ab = Amat + (size_t)b*384;
        float T[12];
#pragma unroll
        for (int e = 0; e < 12; e++) T[e] = 0.f;
#pragma unroll
        for (int j = 0; j < 24; j++) {
#pragma unroll
            for (int e = 0; e < 12; e++)
                T[e] = fmaf(w[j], Ab[j*16 + e], T[e]);
        }
        float vs[3];
#pragma unroll
        for (int m = 0; m < 3; m++) {
            float s = vtv[m];
#pragma unroll
            for (int l = 0; l < 10; l++) s += betas[b*10 + l] * sdv[m*10 + l];
            vs[m] = s;
        }
        int base = b*NCOL + v*3;
        float vp0 = vs[0] + vsh[base + 0];
        float vp1 = vs[1] + vsh[base + 1];
        float vp2 = vs[2] + vsh[base + 2];
#pragma unroll
        for (int m = 0; m < 3; m++) {
            float o = T[m*4+3] + T[m*4]*vp0 + T[m*4+1]*vp1 + T[m*4+2]*vp2;
            out[base + m] = o;
            vsh[base + m] = vs[m];
        }
    }
}

extern "C" void kernel_launch(void* const* d_in, const int* in_sizes, int n_in,
                              void* d_out, int out_size, void* d_ws, size_t ws_size,
                              hipStream_t stream) {
    const float *betas = nullptr, *pose = nullptr, *vt = nullptr, *sd = nullptr,
                *pd = nullptr, *jreg = nullptr, *lbs = nullptr;
    const int* parents = nullptr;
    for (int i = 0; i < n_in; i++) {
        switch (in_sizes[i]) {
            case 10240:   betas = (const float*)d_in[i]; break;      // (1024,10)
            case 73728:   pose  = (const float*)d_in[i]; break;      // (1024,72)
            case 20670:   vt    = (const float*)d_in[i]; break;      // (1,6890,3)
            case 206700:  sd    = (const float*)d_in[i]; break;      // (6890,3,10)
            case 4278690: pd    = (const float*)d_in[i]; break;      // (207,20670)
            case 24:      parents = (const int*)d_in[i]; break;      // (24,)
            case 165360:                                             // (24,6890)/(6890,24)
                if (!jreg) jreg = (const float*)d_in[i];
                else       lbs  = (const float*)d_in[i];
                break;
            default: break;
        }
    }
    float* out = (float*)d_out;
    if (d_ws && ws_size >= (size_t)WS_NEED) {
        // Main path: scratch in workspace; fused all-MFMA GEMM+LBS.
        bf16*     ws_pdt  = (bf16*)((char*)d_ws + WSB_PDT);
        bf16*     ws_pf   = (bf16*)((char*)d_ws + WSB_PF);
        float*    ws_jtjs = (float*)((char*)d_ws + WSB_JTJS);
        ushort_t* ws_whi  = (ushort_t*)((char*)d_ws + WSB_WHI);
        ushort_t* ws_wlo  = (ushort_t*)((char*)d_ws + WSB_WLO);
        k_jtjs<<<24, 256, 0, stream>>>(jreg, vt, sd, ws_jtjs);
        k_transpose<<<dim3(324, 7), 256, 0, stream>>>(pd, ws_pdt);
        k_wpack<<<(VPAD*32 + 255)/256, 256, 0, stream>>>(lbs, ws_whi, ws_wlo);
        k_pose<<<BDIM, 64, 0, stream>>>(betas, pose, parents, ws_jtjs, out, ws_pf);
        k_gemmlbs<<<dim3(108, 32), 256, 0, stream>>>(ws_pf, ws_pdt, betas, sd, vt,
                                                     ws_whi, ws_wlo, out + OUT_A, out);
    } else {
        // Fallback (R1 pipeline): scratch inside the verts region of d_out.
        bf16*  ws_pdt  = (bf16*)(out + SCRF_PDT);
        bf16*  ws_pf   = (bf16*)(out + SCRF_PF);
        float* ws_jtjs = out + SCRF_JTJS;
        k_jtjs<<<24, 256, 0, stream>>>(jreg, vt, sd, ws_jtjs);
        k_transpose<<<dim3(324, 7), 256, 0, stream>>>(pd, ws_pdt);
        k_pose<<<BDIM, 64, 0, stream>>>(betas, pose, parents, ws_jtjs, out, ws_pf);
        k_posegemm<<<dim3(81, 32), 256, 0, stream>>>(ws_pf, ws_pdt, out + OUT_VSHAPED);
        k_lbs<<<dim3(27, BDIM/NB), 256, 0, stream>>>(betas, sd, vt, lbs, out + OUT_A, out);
    }
}